// Round 6
// baseline (254.763 us; speedup 1.0000x reference)
//
#include <hip/hip_runtime.h>
#include <math.h>

// Problem constants (fixed by reference)
#define B_TOT   256
#define N_TOT   2304
#define IN_DIM  8
#define NC      10      // NUM_CLASSES
#define OD      16      // OUT_DIM
#define CD      160     // NC*OD
#define RBIAS   0.1f

// Tiling
#define BTILE    64                      // b per block
#define VB       2                       // b per thread
#define NS       192                     // n-slices (grid.y) -> grid 768 = 3 blocks/CU
#define NPB      (N_TOT / NS)            // 12 n per block
#define NTHREADS 640                     // 32 p × 10 c × 2 dh  (10 waves)
#define CPAD     20                      // class stride in sh_W
#define WROW     (NC * CPAD)             // 200 floats per i-row
#define WBUF     (IN_DIM * WROW)         // 1600 floats per n
#define LROW     13                      // logit row pad
#define NF4      (B_TOT * CD / 4)        // 10240 float4 per partial slab
#define YGRP     8                       // reduce stage-A groups
#define YPER     (NS / YGRP)             // 24 slabs per group

// Packed fp32: d += a*b (2 lanes-of-2); gfx950 fp32 peak requires VOP3P.
#define PKFMA(d, a, b) asm("v_pk_fma_f32 %0, %1, %2, %0" : "+v"(d) : "v"(a), "v"(b))
#define PKADD(d, a)    asm("v_pk_add_f32 %0, %1, %0"     : "+v"(d) : "v"(a))

union F4 { float4 v; float2 h[2]; float f[4]; };

// One routing round, NO atomics. Thread (p,c,dh) owns b=b0+2p+{0,1}, class c,
// d-half dh. W double-buffered in LDS (1 barrier/n); x from global (20 lanes
// share each row -> L1). u/acc/S held as float2 pairs, updated via v_pk_fma_f32.
// Block writes its partial s tile as plain stores; two-stage reduce sums slabs.
// FIRST=1: cw uniform -> acc = plain sum of u; 0.1 scale applied in reduce.
template <int FIRST>
__global__ __launch_bounds__(NTHREADS) void routing_round(
    const float* __restrict__ x,      // [B, N, 8]
    const float* __restrict__ W,      // [N, 8, 160]
    const float* __restrict__ S_acc,  // [B, 160]
    float* __restrict__ part)         // [NS, B, 160]
{
    __shared__ float sh_W[2][WBUF];            // 12.8 KB
    __shared__ float sh_lg[2][BTILE * LROW];   // 6.7 KB

    const int tid = threadIdx.x;
    const int b0  = blockIdx.x * BTILE;
    const int n0  = blockIdx.y * NPB;
    const int p   = tid / 20;
    const int rem = tid - p * 20;
    const int c   = rem >> 1;
    const int dh  = rem & 1;
    const int bl0 = p * VB;

    // S fragment as aligned pairs: [2 b][4 pair]
    float2 S2[VB][4];
    if (!FIRST) {
        #pragma unroll
        for (int j = 0; j < VB; j++) {
            const float2* sp = (const float2*)(S_acc + (size_t)(b0 + bl0 + j) * CD + c * OD + dh * 8);
            #pragma unroll
            for (int q = 0; q < 4; q++) S2[j][q] = sp[q];
        }
    }

    float2 acc2[VB][4];
    #pragma unroll
    for (int j = 0; j < VB; j++)
        #pragma unroll
        for (int q = 0; q < 4; q++) acc2[j][q] = make_float2(0.f, 0.f);

    // W staging: first 5 waves stage one float4 each (1280 floats per n-row)
    const bool stager = (tid < 320);
    const int e4 = tid * 4;
    const int wi = stager ? (e4 / CD) : 0;
    const int wr = stager ? (e4 - wi * CD) : 0;
    const int wc = wr >> 4;
    const int wd = wr & 15;
    const int wlds = wi * WROW + wc * CPAD + wd;
    const float* Wbase = W + (size_t)n0 * (IN_DIM * CD);

    if (stager) {
        float4 wv = *(const float4*)(Wbase + e4);
        *(float4*)&sh_W[0][wlds] = wv;
    }
    __syncthreads();

    for (int nn = 0; nn < NPB; nn++) {
        const int cur = nn & 1, nxt = cur ^ 1;

        float4 wnext;
        if (stager && nn + 1 < NPB)
            wnext = *(const float4*)(Wbase + (size_t)(nn + 1) * (IN_DIM * CD) + e4);

        float2 u2[VB][4];
        #pragma unroll
        for (int j = 0; j < VB; j++)
            #pragma unroll
            for (int q = 0; q < 4; q++) u2[j][q] = make_float2(0.f, 0.f);

        const float* wb = &sh_W[cur][c * CPAD + dh * 8];
        #pragma unroll
        for (int h = 0; h < 2; h++) {           // i-halves cap live x at 2 float4
            F4 xh[VB];
            #pragma unroll
            for (int j = 0; j < VB; j++)
                xh[j].v = *(const float4*)(x + ((size_t)(b0 + bl0 + j) * N_TOT + n0 + nn) * IN_DIM + h * 4);
            #pragma unroll
            for (int i = 0; i < 4; i++) {
                const int ig = h * 4 + i;
                F4 w0, w1;
                w0.v = *(const float4*)(wb + ig * WROW);
                w1.v = *(const float4*)(wb + ig * WROW + 4);
                #pragma unroll
                for (int j = 0; j < VB; j++) {
                    float xv = xh[j].f[i];
                    float2 xx = make_float2(xv, xv);
                    PKFMA(u2[j][0], xx, w0.h[0]);
                    PKFMA(u2[j][1], xx, w0.h[1]);
                    PKFMA(u2[j][2], xx, w1.h[0]);
                    PKFMA(u2[j][3], xx, w1.h[1]);
                }
            }
        }

        float lg[VB];
        if (!FIRST) {
            #pragma unroll
            for (int j = 0; j < VB; j++) {
                float2 lac = make_float2(0.f, 0.f);
                #pragma unroll
                for (int q = 0; q < 4; q++) PKFMA(lac, u2[j][q], S2[j][q]);
                float t = lac.x + lac.y;
                t += __shfl_xor(t, 1, 64);      // partner d-half (adjacent lane)
                lg[j] = t;
            }
            if (dh == 0) {
                #pragma unroll
                for (int j = 0; j < VB; j++)
                    sh_lg[cur][(bl0 + j) * LROW + c] = lg[j];
            }
        }

        if (stager && nn + 1 < NPB)
            *(float4*)&sh_W[nxt][wlds] = wnext;

        __syncthreads();   // the ONLY barrier per n

        if (!FIRST) {
            // dh-split softmax: this thread reduces row bl0+dh only
            const float* row = &sh_lg[cur][(bl0 + dh) * LROW];
            float m = row[0];
            #pragma unroll
            for (int k = 1; k < NC; k++) m = fmaxf(m, row[k]);
            float denom = 0.f;
            #pragma unroll
            for (int k = 0; k < NC; k++) denom += __expf(row[k] - m);
            float cwo = __expf(lg[dh] - m) / denom;     // my (row bl0+dh, class c)
            float cwp = __shfl_xor(cwo, 1, 64);         // partner's row
            float cw[VB];
            cw[dh] = cwo;
            cw[1 - dh] = cwp;
            #pragma unroll
            for (int j = 0; j < VB; j++) {
                float2 cc = make_float2(cw[j], cw[j]);
                #pragma unroll
                for (int q = 0; q < 4; q++) PKFMA(acc2[j][q], cc, u2[j][q]);
            }
        } else {
            #pragma unroll
            for (int j = 0; j < VB; j++)
                #pragma unroll
                for (int q = 0; q < 4; q++) PKADD(acc2[j][q], u2[j][q]);
        }
    }

    // flush: plain coalesced stores to this block's private slab — NO atomics
    float* dst = part + ((size_t)blockIdx.y * B_TOT + (b0 + bl0)) * CD + c * OD + dh * 8;
    #pragma unroll
    for (int j = 0; j < VB; j++) {
        F4 o0; o0.h[0] = acc2[j][0]; o0.h[1] = acc2[j][1];
        F4 o1; o1.h[0] = acc2[j][2]; o1.h[1] = acc2[j][3];
        *(float4*)(dst + (size_t)j * CD)     = o0.v;
        *(float4*)(dst + (size_t)j * CD + 4) = o1.v;
    }
}

// Stage A: block (g-chunk, k) sums slabs y in [k*YPER, (k+1)*YPER) -> part2[k]
__global__ __launch_bounds__(256) void reduceA(
    const float* __restrict__ part,   // [NS, B, 160]
    float* __restrict__ part2)        // [YGRP, B, 160]
{
    int g = blockIdx.x * 256 + threadIdx.x;   // 0..NF4-1
    int k = blockIdx.y;
    const float4* p4 = (const float4*)part + (size_t)k * YPER * NF4 + g;
    float sx = 0.f, sy = 0.f, sz = 0.f, sw = 0.f;
    #pragma unroll 4
    for (int y = 0; y < YPER; y++) {
        float4 t = p4[(size_t)y * NF4];
        sx += t.x; sy += t.y; sz += t.z; sw += t.w;
    }
    float4 o = { sx, sy, sz, sw };
    ((float4*)part2)[(size_t)k * NF4 + g] = o;
}

// Stage B: sums the YGRP group-slabs (+scale +bias); folds into S_acc
// (rounds 0,1) or squashes to output (round 2).
__global__ __launch_bounds__(256) void reduceB(
    const float* __restrict__ part2,  // [YGRP, B, 160]
    float* __restrict__ S_acc,
    float* __restrict__ v_out,
    float scale, int is_final)
{
    int g = blockIdx.x * 256 + threadIdx.x;   // 0..NF4-1
    const float4* p4 = (const float4*)part2;
    float sx = 0.f, sy = 0.f, sz = 0.f, sw = 0.f;
    #pragma unroll
    for (int k = 0; k < YGRP; k++) {
        float4 t = p4[(size_t)k * NF4 + g];
        sx += t.x; sy += t.y; sz += t.z; sw += t.w;
    }
    sx = sx * scale + RBIAS;
    sy = sy * scale + RBIAS;
    sz = sz * scale + RBIAS;
    sw = sw * scale + RBIAS;
    if (!is_final) {
        float4* S4 = (float4*)S_acc;
        float4 o = S4[g];
        o.x += sx; o.y += sy; o.z += sz; o.w += sw;
        S4[g] = o;
    } else {
        // squash over 16 d = 4 consecutive lanes (one (b,c) row)
        float ss = sx * sx + sy * sy + sz * sz + sw * sw;
        ss += __shfl_xor(ss, 1, 64);
        ss += __shfl_xor(ss, 2, 64);
        float norm = sqrtf(ss);
        float k2 = norm / (1.0f + ss);
        float4 v = { sx * k2, sy * k2, sz * k2, sw * k2 };
        ((float4*)v_out)[g] = v;
    }
}

extern "C" void kernel_launch(void* const* d_in, const int* in_sizes, int n_in,
                              void* d_out, int out_size, void* d_ws, size_t ws_size,
                              hipStream_t stream) {
    const float* x = (const float*)d_in[0];   // [256,2304,8]
    const float* W = (const float*)d_in[1];   // [2304,8,160]
    float* out = (float*)d_out;               // [256,10,16]

    float* S_acc = (float*)d_ws;                           // 40960 floats
    float* part  = S_acc + (size_t)B_TOT * CD;             // NS * 40960
    float* part2 = part + (size_t)NS * B_TOT * CD;         // YGRP * 40960

    hipMemsetAsync(S_acc, 0, (size_t)B_TOT * CD * sizeof(float), stream);

    for (int r = 0; r < 3; r++) {
        if (r == 0)
            routing_round<1><<<dim3(B_TOT / BTILE, NS), NTHREADS, 0, stream>>>(x, W, S_acc, part);
        else
            routing_round<0><<<dim3(B_TOT / BTILE, NS), NTHREADS, 0, stream>>>(x, W, S_acc, part);
        reduceA<<<dim3(NF4 / 256, YGRP), 256, 0, stream>>>(part, part2);
        reduceB<<<NF4 / 256, 256, 0, stream>>>(part2, S_acc, out,
                                               r == 0 ? 0.1f : 1.0f, r == 2);
    }
}

// Round 7
// 220.615 us; speedup vs baseline: 1.1548x; 1.1548x over previous
//
#include <hip/hip_runtime.h>
#include <math.h>

// Problem constants (fixed by reference)
#define B_TOT   256
#define N_TOT   2304
#define IN_DIM  8
#define NC      10      // NUM_CLASSES
#define OD      16      // OUT_DIM
#define CD      160     // NC*OD
#define RBIAS   0.1f

// Tiling: wave-per-class layout. Block = 10 waves (c=0..9) × 64 lanes (b).
#define BTILE    64                      // b per block (= wave lanes)
#define NS       192                     // n-slices (grid.y); grid = 4*192 = 768
#define NPB      (N_TOT / NS)            // 12 n per block
#define NTHREADS 640                     // 10 waves
#define XR       (NPB * IN_DIM + 4)      // 100: x row stride (b*100%32 spreads banks)
#define LB       72                      // logit board row stride (8 mod 32 -> clean)
#define NF4      (B_TOT * CD / 4)        // 10240 float4 per partial slab
#define YGRP     8                       // reduce stage-A groups
#define YPER     (NS / YGRP)             // 24 slabs per group

// One routing round. Wave c, lane b. Thread owns u[16] for (b0+b, class c).
// W[n,i,c*16..+16) is wave-uniform -> scalar loads (SGPR), FMA reads W as the
// scalar operand: W never touches LDS/VGPRs. x staged once in LDS (read-only).
// Logits: in-thread dot (all 16 d local), [c][b] LDS board, 1 barrier/iter.
// FIRST=1: cw uniform -> acc += u directly, NO per-iter barrier at all;
// 0.1 scale applied in reduce.
template <int FIRST>
__global__ __launch_bounds__(NTHREADS) void routing_round(
    const float* __restrict__ x,      // [B, N, 8]
    const float* __restrict__ W,      // [N, 8, 160]
    const float* __restrict__ S_acc,  // [B, 160]
    float* __restrict__ part)         // [NS, B, 160]
{
    __shared__ float sh_x[BTILE * XR];            // 25.6 KB
    __shared__ float sh_lg[2][NC * LB];           // 5.8 KB

    const int tid = threadIdx.x;
    const int b0  = blockIdx.x * BTILE;
    const int n0  = blockIdx.y * NPB;
    const int b   = tid & 63;
    // Force wave-uniformity so W indexing becomes scalar (s_load).
    const int cu  = __builtin_amdgcn_readfirstlane(tid >> 6);

    // ---- stage x tile: [64 b][96 floats], coalesced float4
    {
        const int XT4 = BTILE * (NPB * IN_DIM / 4);   // 64*24 = 1536
        for (int k = tid; k < XT4; k += NTHREADS) {
            int bb   = k / (NPB * 2);
            int off4 = k - bb * (NPB * 2);
            float4 v = *(const float4*)(x + ((size_t)(b0 + bb) * N_TOT + n0) * IN_DIM + off4 * 4);
            *(float4*)(&sh_x[bb * XR + off4 * 4]) = v;
        }
    }

    // ---- S fragment: all 16 d for (b, c) — in-thread logit dot later
    float S[OD];
    if (!FIRST) {
        const float4* sp = (const float4*)(S_acc + (size_t)(b0 + b) * CD + cu * OD);
        #pragma unroll
        for (int q = 0; q < 4; q++) ((float4*)S)[q] = sp[q];
    }

    float acc[OD];
    #pragma unroll
    for (int d = 0; d < OD; d++) acc[d] = 0.f;

    __syncthreads();   // sh_x ready

    const float* Wc = W + cu * OD;    // wave-uniform base

    for (int nn = 0; nn < NPB; nn++) {
        // x[b, n0+nn, 0..7] from LDS (2× ds_read_b128, the only per-iter LDS reads)
        float xf[IN_DIM];
        {
            const float4* xp = (const float4*)(&sh_x[b * XR + nn * IN_DIM]);
            ((float4*)xf)[0] = xp[0];
            ((float4*)xf)[1] = xp[1];
        }

        // u[16] = sum_i x_i * W[n,i,c*16+d]  — W operand is SGPR (scalar loads)
        const float* Wn = Wc + (size_t)(n0 + nn) * (IN_DIM * CD);
        float u[OD];
        #pragma unroll
        for (int d = 0; d < OD; d++) u[d] = xf[0] * Wn[d];
        #pragma unroll
        for (int i = 1; i < IN_DIM; i++) {
            const float* Wi = Wn + i * CD;
            #pragma unroll
            for (int d = 0; d < OD; d++) u[d] = fmaf(xf[i], Wi[d], u[d]);
        }

        if (!FIRST) {
            const int cur = nn & 1;
            // logit fully in-thread
            float lg = 0.f;
            #pragma unroll
            for (int d = 0; d < OD; d++) lg = fmaf(u[d], S[d], lg);
            sh_lg[cur][cu * LB + b] = lg;
            __syncthreads();   // board ready (also separates from iter nn-2 reads)

            // softmax over the 10 classes for row b
            float m = -1e30f;
            float row[NC];
            #pragma unroll
            for (int k = 0; k < NC; k++) {
                row[k] = sh_lg[cur][k * LB + b];
                m = fmaxf(m, row[k]);
            }
            float den = 0.f;
            #pragma unroll
            for (int k = 0; k < NC; k++) den += __expf(row[k] - m);
            float cw = __expf(lg - m) / den;

            #pragma unroll
            for (int d = 0; d < OD; d++) acc[d] = fmaf(cw, u[d], acc[d]);
        } else {
            #pragma unroll
            for (int d = 0; d < OD; d++) acc[d] += u[d];   // 0.1 folded in reduce
        }
    }

    // flush: plain stores to this block's private slab — NO atomics
    float* dst = part + ((size_t)blockIdx.y * B_TOT + (b0 + b)) * CD + cu * OD;
    #pragma unroll
    for (int q = 0; q < 4; q++)
        ((float4*)dst)[q] = ((float4*)acc)[q];
}

// Stage A: block (g-chunk, k) sums slabs y in [k*YPER, (k+1)*YPER) -> part2[k]
__global__ __launch_bounds__(256) void reduceA(
    const float* __restrict__ part,   // [NS, B, 160]
    float* __restrict__ part2)        // [YGRP, B, 160]
{
    int g = blockIdx.x * 256 + threadIdx.x;   // 0..NF4-1
    int k = blockIdx.y;
    const float4* p4 = (const float4*)part + (size_t)k * YPER * NF4 + g;
    float sx = 0.f, sy = 0.f, sz = 0.f, sw = 0.f;
    #pragma unroll 4
    for (int y = 0; y < YPER; y++) {
        float4 t = p4[(size_t)y * NF4];
        sx += t.x; sy += t.y; sz += t.z; sw += t.w;
    }
    float4 o = { sx, sy, sz, sw };
    ((float4*)part2)[(size_t)k * NF4 + g] = o;
}

// Stage B: sums the YGRP group-slabs (+scale +bias); folds into S_acc
// (rounds 0,1) or squashes to output (round 2).
__global__ __launch_bounds__(256) void reduceB(
    const float* __restrict__ part2,  // [YGRP, B, 160]
    float* __restrict__ S_acc,
    float* __restrict__ v_out,
    float scale, int is_final)
{
    int g = blockIdx.x * 256 + threadIdx.x;   // 0..NF4-1
    const float4* p4 = (const float4*)part2;
    float sx = 0.f, sy = 0.f, sz = 0.f, sw = 0.f;
    #pragma unroll
    for (int k = 0; k < YGRP; k++) {
        float4 t = p4[(size_t)k * NF4 + g];
        sx += t.x; sy += t.y; sz += t.z; sw += t.w;
    }
    sx = sx * scale + RBIAS;
    sy = sy * scale + RBIAS;
    sz = sz * scale + RBIAS;
    sw = sw * scale + RBIAS;
    if (!is_final) {
        float4* S4 = (float4*)S_acc;
        float4 o = S4[g];
        o.x += sx; o.y += sy; o.z += sz; o.w += sw;
        S4[g] = o;
    } else {
        // squash over 16 d = 4 consecutive lanes (one (b,c) row)
        float ss = sx * sx + sy * sy + sz * sz + sw * sw;
        ss += __shfl_xor(ss, 1, 64);
        ss += __shfl_xor(ss, 2, 64);
        float norm = sqrtf(ss);
        float k2 = norm / (1.0f + ss);
        float4 v = { sx * k2, sy * k2, sz * k2, sw * k2 };
        ((float4*)v_out)[g] = v;
    }
}

extern "C" void kernel_launch(void* const* d_in, const int* in_sizes, int n_in,
                              void* d_out, int out_size, void* d_ws, size_t ws_size,
                              hipStream_t stream) {
    const float* x = (const float*)d_in[0];   // [256,2304,8]
    const float* W = (const float*)d_in[1];   // [2304,8,160]
    float* out = (float*)d_out;               // [256,10,16]

    float* S_acc = (float*)d_ws;                           // 40960 floats
    float* part  = S_acc + (size_t)B_TOT * CD;             // NS * 40960
    float* part2 = part + (size_t)NS * B_TOT * CD;         // YGRP * 40960

    hipMemsetAsync(S_acc, 0, (size_t)B_TOT * CD * sizeof(float), stream);

    for (int r = 0; r < 3; r++) {
        if (r == 0)
            routing_round<1><<<dim3(B_TOT / BTILE, NS), NTHREADS, 0, stream>>>(x, W, S_acc, part);
        else
            routing_round<0><<<dim3(B_TOT / BTILE, NS), NTHREADS, 0, stream>>>(x, W, S_acc, part);
        reduceA<<<dim3(NF4 / 256, YGRP), 256, 0, stream>>>(part, part2);
        reduceB<<<NF4 / 256, 256, 0, stream>>>(part2, S_acc, out,
                                               r == 0 ? 0.1f : 1.0f, r == 2);
    }
}